// Round 1
// baseline (111.361 us; speedup 1.0000x reference)
//
#include <hip/hip_runtime.h>
#include <math.h>

// PLIF (parametric LIF) forward, heterogeneous per-feature decay/threshold.
// x: [B=4, N=1024, T=128, D=128] fp32, scan over T per (b,n,d) chain.
//   v = v * sigmoid(decay[d]) + x[t]
//   s = (v - (sigmoid(v_th[d]) + 0.1)) > 0 ? 1 : 0
//   v = s ? 0 : v        (hard reset; exact since s in {0,1})
// Output spikes, same layout as x.
//
// One thread owns 4 adjacent features (one float4 lane) of one (b,n) row and
// walks T in registers. Loads/stores are float4 (16B/lane), coalesced across
// the wave (lanes cover contiguous D within a row).
//
// __fmul_rn/__fadd_rn/__fsub_rn prevent fma contraction so the fp32 rounding
// matches the mul-then-add reference exactly (spike compares are boundary-
// sensitive: one ulp flip -> absmax 1.0).

#define T_STEPS 128
#define D_FEAT  128
#define GROUPS  (D_FEAT / 4)   // 32 float4 groups per (b,n) row

__global__ __launch_bounds__(256)
void plif_fwd_kernel(const float4* __restrict__ x,
                     const float*  __restrict__ decay,
                     const float*  __restrict__ vth,
                     float4* __restrict__ out)
{
    const int tid = blockIdx.x * blockDim.x + threadIdx.x;
    const int g   = tid & (GROUPS - 1);   // float4 group within D
    const int row = tid >> 5;             // b*N + n

    const size_t base = (size_t)row * (size_t)T_STEPS * GROUPS + (size_t)g;
    const float4* __restrict__ xr = x + base;
    float4* __restrict__       orw = out + base;

    // per-feature constants (8 expf per thread -- negligible)
    const int d0 = g * 4;
    float dec0 = 1.0f / (1.0f + expf(-decay[d0 + 0]));
    float dec1 = 1.0f / (1.0f + expf(-decay[d0 + 1]));
    float dec2 = 1.0f / (1.0f + expf(-decay[d0 + 2]));
    float dec3 = 1.0f / (1.0f + expf(-decay[d0 + 3]));
    float th0  = 1.0f / (1.0f + expf(-vth[d0 + 0])) + 0.1f;
    float th1  = 1.0f / (1.0f + expf(-vth[d0 + 1])) + 0.1f;
    float th2  = 1.0f / (1.0f + expf(-vth[d0 + 2])) + 0.1f;
    float th3  = 1.0f / (1.0f + expf(-vth[d0 + 3])) + 0.1f;

    float v0 = 0.0f, v1 = 0.0f, v2 = 0.0f, v3 = 0.0f;

#pragma unroll 4
    for (int t = 0; t < T_STEPS; ++t) {
        const float4 xv = xr[(size_t)t * GROUPS];

        // chain 0
        v0 = __fadd_rn(__fmul_rn(v0, dec0), xv.x);
        const float s0 = (__fsub_rn(v0, th0) > 0.0f) ? 1.0f : 0.0f;
        v0 = (s0 != 0.0f) ? 0.0f : v0;
        // chain 1
        v1 = __fadd_rn(__fmul_rn(v1, dec1), xv.y);
        const float s1 = (__fsub_rn(v1, th1) > 0.0f) ? 1.0f : 0.0f;
        v1 = (s1 != 0.0f) ? 0.0f : v1;
        // chain 2
        v2 = __fadd_rn(__fmul_rn(v2, dec2), xv.z);
        const float s2 = (__fsub_rn(v2, th2) > 0.0f) ? 1.0f : 0.0f;
        v2 = (s2 != 0.0f) ? 0.0f : v2;
        // chain 3
        v3 = __fadd_rn(__fmul_rn(v3, dec3), xv.w);
        const float s3 = (__fsub_rn(v3, th3) > 0.0f) ? 1.0f : 0.0f;
        v3 = (s3 != 0.0f) ? 0.0f : v3;

        orw[(size_t)t * GROUPS] = make_float4(s0, s1, s2, s3);
    }
}

extern "C" void kernel_launch(void* const* d_in, const int* in_sizes, int n_in,
                              void* d_out, int out_size, void* d_ws, size_t ws_size,
                              hipStream_t stream)
{
    const float* x     = (const float*)d_in[0];
    const float* decay = (const float*)d_in[1];
    const float* vth   = (const float*)d_in[2];
    float*       out   = (float*)d_out;

    const int total   = in_sizes[0];                    // B*N*T*D = 67108864
    const int rows    = total / (T_STEPS * D_FEAT);     // B*N = 4096
    const int threads = rows * GROUPS;                  // 131072
    const int block   = 256;

    plif_fwd_kernel<<<threads / block, block, 0, stream>>>(
        (const float4*)x, decay, vth, (float4*)out);
}

// Round 3
// 104.176 us; speedup vs baseline: 1.0690x; 1.0690x over previous
//
#include <hip/hip_runtime.h>
#include <math.h>

// PLIF (parametric LIF) forward, heterogeneous per-feature decay/threshold.
// x: [B=4, N=1024, T=128, D=128] fp32, sequential scan over T per (b,n,d):
//   v = v * sigmoid(decay[d]) + x[t]
//   s = (v > sigmoid(v_th[d]) + 0.1) ? 1 : 0
//   v = s ? 0 : v        (hard reset; exact since s in {0,1})
//
// R2: float2-per-thread (262144 threads -> 4 waves/SIMD, 2x TLP vs R0's
//     float4 version), unroll 8 (8 loads in flight/thread), nontemporal
//     load/store (streaming 512 MB once -- don't pollute the 256 MB L3).
//     R2 fix: nontemporal builtins need a true clang vector type, not
//     HIP_vector_type -- use ext_vector_type(2) alias.
//
// __fmul_rn/__fadd_rn prevent fma contraction so fp32 rounding matches the
// mul-then-add numpy reference exactly (spike compares are boundary-
// sensitive: one ulp flip -> absmax 1.0). R1 passed with absmax 0.0.

#define T_STEPS 128
#define D_FEAT  128
#define GROUPS  (D_FEAT / 2)   // 64 float2 groups per (b,n) row

typedef float f32x2 __attribute__((ext_vector_type(2)));

__global__ __launch_bounds__(256)
void plif_fwd_kernel(const f32x2* __restrict__ x,
                     const float* __restrict__ decay,
                     const float* __restrict__ vth,
                     f32x2* __restrict__ out)
{
    const int tid = blockIdx.x * blockDim.x + threadIdx.x;
    const int g   = tid & (GROUPS - 1);   // float2 group within D
    const int row = tid >> 6;             // b*N + n

    const size_t base = (size_t)row * (size_t)T_STEPS * GROUPS + (size_t)g;
    const f32x2* __restrict__ xr  = x + base;
    f32x2* __restrict__       orw = out + base;

    // per-feature constants (4 expf per thread -- negligible)
    const int d0 = g * 2;
    const float dec0 = 1.0f / (1.0f + expf(-decay[d0 + 0]));
    const float dec1 = 1.0f / (1.0f + expf(-decay[d0 + 1]));
    const float th0  = 1.0f / (1.0f + expf(-vth[d0 + 0])) + 0.1f;
    const float th1  = 1.0f / (1.0f + expf(-vth[d0 + 1])) + 0.1f;

    float v0 = 0.0f, v1 = 0.0f;

#pragma unroll 8
    for (int t = 0; t < T_STEPS; ++t) {
        const f32x2 xv = __builtin_nontemporal_load(xr + (size_t)t * GROUPS);

        // chain 0
        v0 = __fadd_rn(__fmul_rn(v0, dec0), xv.x);
        const bool f0 = (v0 > th0);
        const float s0 = f0 ? 1.0f : 0.0f;
        v0 = f0 ? 0.0f : v0;
        // chain 1
        v1 = __fadd_rn(__fmul_rn(v1, dec1), xv.y);
        const bool f1 = (v1 > th1);
        const float s1 = f1 ? 1.0f : 0.0f;
        v1 = f1 ? 0.0f : v1;

        f32x2 sv;
        sv.x = s0;
        sv.y = s1;
        __builtin_nontemporal_store(sv, orw + (size_t)t * GROUPS);
    }
}

extern "C" void kernel_launch(void* const* d_in, const int* in_sizes, int n_in,
                              void* d_out, int out_size, void* d_ws, size_t ws_size,
                              hipStream_t stream)
{
    const float* x     = (const float*)d_in[0];
    const float* decay = (const float*)d_in[1];
    const float* vth   = (const float*)d_in[2];
    float*       out   = (float*)d_out;

    const int total   = in_sizes[0];                    // B*N*T*D = 67108864
    const int rows    = total / (T_STEPS * D_FEAT);     // B*N = 4096
    const int threads = rows * GROUPS;                  // 262144
    const int block   = 256;

    plif_fwd_kernel<<<threads / block, block, 0, stream>>>(
        (const f32x2*)x, decay, vth, (f32x2*)out);
}